// Round 1
// baseline (31023.447 us; speedup 1.0000x reference)
//
#include <hip/hip_runtime.h>
#include <hip/hip_bf16.h>

#define TSTEPS 256
#define B 128
#define D 1024
#define G3 3072
#define BD (B * D)

typedef __attribute__((ext_vector_type(8))) short bf16x8;
typedef __attribute__((ext_vector_type(4))) float f32x4;

__device__ __forceinline__ unsigned short f2bf(float f) {
    __hip_bfloat16 h = __float2bfloat16(f);
    return *reinterpret_cast<unsigned short*>(&h);
}

// -------- fp32 -> bf16 conversion (weights) --------
__global__ __launch_bounds__(256) void cvt_f32_bf16(const float* __restrict__ in,
                                                    unsigned short* __restrict__ out, int n) {
    int i = (blockIdx.x * 256 + threadIdx.x) * 8;
    if (i + 8 <= n) {
        float4 a = *(const float4*)(in + i);
        float4 b = *(const float4*)(in + i + 4);
        unsigned short t[8] = { f2bf(a.x), f2bf(a.y), f2bf(a.z), f2bf(a.w),
                                f2bf(b.x), f2bf(b.y), f2bf(b.z), f2bf(b.w) };
        *(uint4*)(out + i) = *(const uint4*)t;
    }
}

// -------- fused GRU cell: gates GEMM (bf16 MFMA) + pointwise --------
// grid: (2, 64)  -> blockIdx.x = 64-row half of batch, blockIdx.y = 16-output-col block
// block: 256 threads = 4 waves; wave w handles rows [bx*64 + w*16, +16)
// Computes, for its 16 output cols (j) and 64 rows (b):
//   gi = hin @ Wih^T   (3 gates, separate acc)
//   gh = hprev @ Whh^T (3 gates, separate acc)
//   r = sig(gi_r+b_ir+gh_r+b_hr); z = sig(...); n = tanh(gi_n+b_in + r*(gh_n+b_hn))
//   h = (1-z)*n + z*hprev ; y = lrelu((h + hin)*RES_NORM, 0.2)
template<bool AIN_F32>
__global__ __launch_bounds__(256) void gru_cell(
    const void* __restrict__ ain,              // [128,1024] bf16 (ushort) or f32
    const unsigned short* __restrict__ aprev,  // [128,1024] bf16
    const unsigned short* __restrict__ Wih,    // [3072,1024] bf16 (layer base)
    const unsigned short* __restrict__ Whh,    // [3072,1024] bf16
    const float* __restrict__ bih,             // [3072]
    const float* __restrict__ bhh,             // [3072]
    const float* __restrict__ hin_f32,         // [128,1024] residual input (f32)
    const float* __restrict__ hprev_f32,       // [128,1024]
    float* __restrict__ hout_f32,
    unsigned short* __restrict__ hout_bf,
    float* __restrict__ hinnext_f32,
    unsigned short* __restrict__ hinnext_bf)
{
    __shared__ __align__(16) unsigned short sAin[64 * 72];
    __shared__ __align__(16) unsigned short sApr[64 * 72];
    __shared__ __align__(16) unsigned short sWih[48 * 72];
    __shared__ __align__(16) unsigned short sWhh[48 * 72];

    const int tid  = threadIdx.x;
    const int wave = tid >> 6;
    const int lane = tid & 63;
    const int bx   = blockIdx.x;       // 0/1 : 64-row half
    const int c0   = blockIdx.y * 16;  // output-col base

    f32x4 acc_i[3] = {f32x4{0,0,0,0}, f32x4{0,0,0,0}, f32x4{0,0,0,0}};
    f32x4 acc_h[3] = {f32x4{0,0,0,0}, f32x4{0,0,0,0}, f32x4{0,0,0,0}};

    for (int ks = 0; ks < D; ks += 64) {
        // ---- stage A tiles: 64 rows x 64 k (8 bf16 per thread-vec, 512 vecs each)
        #pragma unroll
        for (int i = 0; i < 2; ++i) {
            int v   = tid + i * 256;      // 0..511
            int row = v >> 3;             // 0..63
            int k8  = (v & 7) * 8;
            int grow = bx * 64 + row;
            if (AIN_F32) {
                const float* src = (const float*)ain + (size_t)grow * D + ks + k8;
                float4 a = *(const float4*)src;
                float4 b = *(const float4*)(src + 4);
                unsigned short t[8] = { f2bf(a.x), f2bf(a.y), f2bf(a.z), f2bf(a.w),
                                        f2bf(b.x), f2bf(b.y), f2bf(b.z), f2bf(b.w) };
                *(uint4*)&sAin[row * 72 + k8] = *(const uint4*)t;
            } else {
                const unsigned short* src = (const unsigned short*)ain + (size_t)grow * D + ks + k8;
                *(uint4*)&sAin[row * 72 + k8] = *(const uint4*)src;
            }
            const unsigned short* sp = aprev + (size_t)grow * D + ks + k8;
            *(uint4*)&sApr[row * 72 + k8] = *(const uint4*)sp;
        }
        // ---- stage W tiles: 48 rows (3 gates x 16 cols) x 64 k = 384 vecs
        #pragma unroll
        for (int i = 0; i < 2; ++i) {
            int v = tid + i * 256;
            if (v < 384) {
                int row = v >> 3;         // 0..47
                int k8  = (v & 7) * 8;
                int g   = row >> 4;
                int r   = row & 15;
                size_t wrow = (size_t)(g * D + c0 + r) * D + ks + k8;
                *(uint4*)&sWih[row * 72 + k8] = *(const uint4*)(Wih + wrow);
                *(uint4*)&sWhh[row * 72 + k8] = *(const uint4*)(Whh + wrow);
            }
        }
        __syncthreads();

        const int arow  = (wave << 4) + (lane & 15);
        const int klane = (lane >> 4) << 3;
        #pragma unroll
        for (int kk = 0; kk < 2; ++kk) {
            int ko = kk * 32 + klane;
            bf16x8 fai = *(const bf16x8*)&sAin[arow * 72 + ko];
            bf16x8 fap = *(const bf16x8*)&sApr[arow * 72 + ko];
            #pragma unroll
            for (int g = 0; g < 3; ++g) {
                int wrow = (g << 4) + (lane & 15);
                bf16x8 fbi = *(const bf16x8*)&sWih[wrow * 72 + ko];
                bf16x8 fbh = *(const bf16x8*)&sWhh[wrow * 72 + ko];
                acc_i[g] = __builtin_amdgcn_mfma_f32_16x16x32_bf16(fai, fbi, acc_i[g], 0, 0, 0);
                acc_h[g] = __builtin_amdgcn_mfma_f32_16x16x32_bf16(fap, fbh, acc_h[g], 0, 0, 0);
            }
        }
        __syncthreads();
    }

    // ---- pointwise gates + residual
    const int col = c0 + (lane & 15);
    const float b_ir = bih[col],         b_hr = bhh[col];
    const float b_iz = bih[D + col],     b_hz = bhh[D + col];
    const float b_in = bih[2 * D + col], b_hn = bhh[2 * D + col];
    const int browbase = bx * 64 + (wave << 4) + ((lane >> 4) << 2);

    #pragma unroll
    for (int q = 0; q < 4; ++q) {
        int idx = (browbase + q) * D + col;
        float r = 1.f / (1.f + __expf(-(acc_i[0][q] + b_ir + acc_h[0][q] + b_hr)));
        float z = 1.f / (1.f + __expf(-(acc_i[1][q] + b_iz + acc_h[1][q] + b_hz)));
        float n = tanhf(acc_i[2][q] + b_in + r * (acc_h[2][q] + b_hn));
        float hp = hprev_f32[idx];
        float h  = (1.f - z) * n + z * hp;
        hout_f32[idx] = h;
        hout_bf[idx]  = f2bf(h);
        float v = (h + hin_f32[idx]) * 0.70710678f;
        float y = v > 0.f ? v : 0.2f * v;
        hinnext_f32[idx] = y;
        hinnext_bf[idx]  = f2bf(y);
    }
}

extern "C" void kernel_launch(void* const* d_in, const int* in_sizes, int n_in,
                              void* d_out, int out_size, void* d_ws, size_t ws_size,
                              hipStream_t stream) {
    const float* x    = (const float*)d_in[0];  // [1,256,128,1024]
    const float* Wih  = (const float*)d_in[1];  // [3,3072,1024]
    const float* Whh  = (const float*)d_in[2];
    const float* bih  = (const float*)d_in[3];  // [3,3072]
    const float* bhh  = (const float*)d_in[4];
    float* out = (float*)d_out;

    char* ws = (char*)d_ws;
    size_t off = 0;
    auto alloc = [&](size_t bytes) -> void* {
        void* p = ws + off;
        off += (bytes + 255) & ~(size_t)255;
        return p;
    };

    const size_t WBYTES = (size_t)3 * G3 * D * 2;  // 18.87 MB
    unsigned short* Wih_bf = (unsigned short*)alloc(WBYTES);
    unsigned short* Whh_bf = (unsigned short*)alloc(WBYTES);

    // rings (contiguous, one memset): bf16 then f32
    const int R[3] = {2, 3, 5};
    size_t ring_start = off;
    unsigned short* hr_bf[3];
    float* hr_f[3];
    for (int l = 0; l < 3; ++l) hr_bf[l] = (unsigned short*)alloc((size_t)R[l] * BD * 2);
    for (int l = 0; l < 3; ++l) hr_f[l]  = (float*)alloc((size_t)R[l] * BD * 4);
    size_t ring_bytes = off - ring_start;

    unsigned short* hin_bf[2] = { (unsigned short*)alloc((size_t)BD * 2),
                                  (unsigned short*)alloc((size_t)BD * 2) };
    float* hin_f[2] = { (float*)alloc((size_t)BD * 4), (float*)alloc((size_t)BD * 4) };
    unsigned short* sink_bf = (unsigned short*)alloc((size_t)BD * 2);

    // convert weights to bf16 (every call; cheap, deterministic)
    const int nW = 3 * G3 * D;  // 9,437,184
    cvt_f32_bf16<<<nW / 8 / 256, 256, 0, stream>>>(Wih, Wih_bf, nW);
    cvt_f32_bf16<<<nW / 8 / 256, 256, 0, stream>>>(Whh, Whh_bf, nW);

    // zero all hidden rings
    hipMemsetAsync(ws + ring_start, 0, ring_bytes, stream);

    dim3 grid(2, 64);
    for (int t = 0; t < TSTEPS; ++t) {
        const float* xt = x + (size_t)t * BD;
        // read slot = (t - dil) mod R == (t+1) mod R for all three layers
        int w0 = t % 2, r0 = (t + 1) % 2;
        int w1 = t % 3, r1 = (t + 1) % 3;
        int w2 = t % 5, r2 = (t + 1) % 5;

        // layer 0: ain = x_t (f32), residual input = x_t
        gru_cell<true><<<grid, 256, 0, stream>>>(
            (const void*)xt, hr_bf[0] + (size_t)r0 * BD,
            Wih_bf, Whh_bf, bih, bhh,
            xt, hr_f[0] + (size_t)r0 * BD,
            hr_f[0] + (size_t)w0 * BD, hr_bf[0] + (size_t)w0 * BD,
            hin_f[0], hin_bf[0]);

        // layer 1
        gru_cell<false><<<grid, 256, 0, stream>>>(
            (const void*)hin_bf[0], hr_bf[1] + (size_t)r1 * BD,
            Wih_bf + (size_t)G3 * D, Whh_bf + (size_t)G3 * D, bih + G3, bhh + G3,
            hin_f[0], hr_f[1] + (size_t)r1 * BD,
            hr_f[1] + (size_t)w1 * BD, hr_bf[1] + (size_t)w1 * BD,
            hin_f[1], hin_bf[1]);

        // layer 2: hinnext_f32 -> d_out[t]
        gru_cell<false><<<grid, 256, 0, stream>>>(
            (const void*)hin_bf[1], hr_bf[2] + (size_t)r2 * BD,
            Wih_bf + (size_t)2 * G3 * D, Whh_bf + (size_t)2 * G3 * D, bih + 2 * G3, bhh + 2 * G3,
            hin_f[1], hr_f[2] + (size_t)r2 * BD,
            hr_f[2] + (size_t)w2 * BD, hr_bf[2] + (size_t)w2 * BD,
            out + (size_t)t * BD, sink_bf);
    }
}

// Round 2
// 17507.932 us; speedup vs baseline: 1.7720x; 1.7720x over previous
//
#include <hip/hip_runtime.h>
#include <hip/hip_bf16.h>

#define TT 256
#define D 1024
#define BD (128 * 1024)
#define NWPL 85
#define NWG (3 * NWPL)
#define STEPS (TT + 2)
#define ROWLEN 1032  // 1024 + 8 bf16 pad (bank-conflict break, keeps 16B align)

typedef __attribute__((ext_vector_type(8))) short bf16x8;
typedef __attribute__((ext_vector_type(4))) float f32x4;

__device__ __forceinline__ unsigned short f2bf(float f) {
    __hip_bfloat16 h = __float2bfloat16(f);
    return *reinterpret_cast<unsigned short*>(&h);
}

__global__ __launch_bounds__(256) void cvt_f32_bf16(const float* __restrict__ in,
                                                    unsigned short* __restrict__ out, int n) {
    int i = (blockIdx.x * 256 + threadIdx.x) * 8;
    if (i + 8 <= n) {
        float4 a = *(const float4*)(in + i);
        float4 b = *(const float4*)(in + i + 4);
        unsigned short t[8] = { f2bf(a.x), f2bf(a.y), f2bf(a.z), f2bf(a.w),
                                f2bf(b.x), f2bf(b.y), f2bf(b.z), f2bf(b.w) };
        *(uint4*)(out + i) = *(const uint4*)t;
    }
}

__device__ __forceinline__ void gbar(unsigned* cnt, unsigned* gen, unsigned nwg) {
    __syncthreads();
    if (threadIdx.x == 0) {
        __threadfence();
        unsigned g = __hip_atomic_load(gen, __ATOMIC_RELAXED, __HIP_MEMORY_SCOPE_AGENT);
        unsigned a = __hip_atomic_fetch_add(cnt, 1u, __ATOMIC_ACQ_REL, __HIP_MEMORY_SCOPE_AGENT);
        if (a == nwg - 1u) {
            __hip_atomic_store(cnt, 0u, __ATOMIC_RELAXED, __HIP_MEMORY_SCOPE_AGENT);
            __hip_atomic_store(gen, g + 1u, __ATOMIC_RELEASE, __HIP_MEMORY_SCOPE_AGENT);
        } else {
            while (__hip_atomic_load(gen, __ATOMIC_ACQUIRE, __HIP_MEMORY_SCOPE_AGENT) == g)
                __builtin_amdgcn_s_sleep(2);
        }
        __threadfence();
    }
    __syncthreads();
}

// Persistent skewed dilated-GRU. 255 WGs = 3 layers x 85 col-slices.
// Each WG: weights (its 12-13 cols x 3 gates x {Wih,Whh}) stationary in LDS.
// Step s computes cells (0,s), (1,s-1), (2,s-2); one grid barrier per step.
__global__ __launch_bounds__(256, 1) void dgru_persistent(
    const unsigned short* __restrict__ xbf, const float* __restrict__ xf,
    const float* __restrict__ Wih, const float* __restrict__ Whh,
    const float* __restrict__ bih, const float* __restrict__ bhh,
    unsigned short* __restrict__ ring_bf, float* __restrict__ ring_f,
    unsigned short* __restrict__ hin_bf, float* __restrict__ hin_f,
    float* __restrict__ out,
    unsigned* __restrict__ bar_cnt, unsigned* __restrict__ bar_gen)
{
    __shared__ unsigned short wlds[78 * ROWLEN];  // 160,992 B

    const int layer = blockIdx.x / NWPL;
    const int u     = blockIdx.x % NWPL;
    const int ncols = (u < 4) ? 13 : 12;
    const int c0    = u * 12 + (u < 4 ? u : 4);

    // ---- one-time: load this WG's weight slice fp32 -> bf16 -> LDS
    {
        const float* w0 = Wih + (size_t)layer * 3 * D * D;
        const float* w1 = Whh + (size_t)layer * 3 * D * D;
        const int nrows = 6 * ncols;
        for (int rid = 0; rid < nrows; ++rid) {
            int m   = rid / (3 * ncols);
            int rem = rid - m * 3 * ncols;
            int g   = rem / ncols;
            int c   = rem - g * ncols;
            const float* src = (m ? w1 : w0) + ((size_t)g * D + c0 + c) * D + threadIdx.x * 4;
            float4 v = *(const float4*)src;
            ushort4 o = { f2bf(v.x), f2bf(v.y), f2bf(v.z), f2bf(v.w) };
            *(ushort4*)&wlds[rid * ROWLEN + threadIdx.x * 4] = o;
        }
        __syncthreads();
    }

    const int tid  = threadIdx.x;
    const int wave = tid >> 6;
    const int lane = tid & 63;
    const int r15  = lane & 15;
    const int kq   = lane >> 4;
    const int kq8  = kq * 8;
    const int c_cl = (r15 < ncols) ? r15 : (ncols - 1);
    const bool cvalid = r15 < ncols;
    const int col  = c0 + c_cl;

    const float bi0 = bih[layer * 3 * D + col];
    const float bi1 = bih[layer * 3 * D + D + col];
    const float bi2 = bih[layer * 3 * D + 2 * D + col];
    const float bh0 = bhh[layer * 3 * D + col];
    const float bh1 = bhh[layer * 3 * D + D + col];
    const float bh2 = bhh[layer * 3 * D + 2 * D + col];

    const unsigned short* bp[6];
    #pragma unroll
    for (int mg = 0; mg < 6; ++mg) bp[mg] = wlds + (mg * ncols + c_cl) * ROWLEN;

    const int arow_off0 = (wave * 32 + r15) * D;
    const int arow_off1 = (wave * 32 + 16 + r15) * D;

    const int R  = (layer == 0) ? 2 : (layer == 1 ? 3 : 5);
    const int rb = (layer == 0) ? 0 : (layer == 1 ? 2 : 5);

    for (int s = 0; s < STEPS; ++s) {
        const int t = s - layer;
        if (t >= 0 && t < TT) {
            const unsigned short* hinb  = layer ? hin_bf + (size_t)((layer - 1) * 2 + (t & 1)) * BD
                                                : xbf + (size_t)t * BD;
            const float* residf         = layer ? hin_f + (size_t)((layer - 1) * 2 + (t & 1)) * BD
                                                : xf + (size_t)t * BD;
            const int rs = (t + 1) % R, wsl = t % R;
            const unsigned short* hprevb = ring_bf + (size_t)(rb + rs) * BD;
            const float*  hprevf = ring_f + (size_t)(rb + rs) * BD;
            float*        houtf  = ring_f + (size_t)(rb + wsl) * BD;
            unsigned short* houtb = ring_bf + (size_t)(rb + wsl) * BD;

            f32x4 acc[2][2][3] = {};
            bf16x8 B0[6], B1[6], A0[4], A1[4];

#define LDB(Bv, KS) { _Pragma("unroll") for (int mg = 0; mg < 6; ++mg) \
        Bv[mg] = *(const bf16x8*)(bp[mg] + (KS) * 32 + kq8); }
#define LDA(Av, KS) { \
        Av[0] = *(const bf16x8*)(hinb   + arow_off0 + (KS) * 32 + kq8); \
        Av[1] = *(const bf16x8*)(hprevb + arow_off0 + (KS) * 32 + kq8); \
        Av[2] = *(const bf16x8*)(hinb   + arow_off1 + (KS) * 32 + kq8); \
        Av[3] = *(const bf16x8*)(hprevb + arow_off1 + (KS) * 32 + kq8); }
#define FM(Av, Bv) { _Pragma("unroll") for (int g = 0; g < 3; ++g) { \
        acc[0][0][g] = __builtin_amdgcn_mfma_f32_16x16x32_bf16(Av[0], Bv[g],     acc[0][0][g], 0, 0, 0); \
        acc[0][1][g] = __builtin_amdgcn_mfma_f32_16x16x32_bf16(Av[1], Bv[3 + g], acc[0][1][g], 0, 0, 0); \
        acc[1][0][g] = __builtin_amdgcn_mfma_f32_16x16x32_bf16(Av[2], Bv[g],     acc[1][0][g], 0, 0, 0); \
        acc[1][1][g] = __builtin_amdgcn_mfma_f32_16x16x32_bf16(Av[3], Bv[3 + g], acc[1][1][g], 0, 0, 0); } }

            LDB(B0, 0); LDA(A0, 0);
            #pragma unroll 1
            for (int ks = 0; ks < 32; ks += 2) {
                LDB(B1, ks + 1); LDA(A1, ks + 1);
                FM(A0, B0);
                if (ks < 30) { LDB(B0, ks + 2); LDA(A0, ks + 2); }
                FM(A1, B1);
            }

            #pragma unroll
            for (int rtl = 0; rtl < 2; ++rtl) {
                #pragma unroll
                for (int q = 0; q < 4; ++q) {
                    const int row = wave * 32 + rtl * 16 + kq * 4 + q;
                    const size_t idx = (size_t)row * D + col;
                    float xr = acc[rtl][0][0][q] + bi0 + acc[rtl][1][0][q] + bh0;
                    float xz = acc[rtl][0][1][q] + bi1 + acc[rtl][1][1][q] + bh1;
                    float rg = 1.f / (1.f + __expf(-xr));
                    float zg = 1.f / (1.f + __expf(-xz));
                    float ng = tanhf(acc[rtl][0][2][q] + bi2 + rg * (acc[rtl][1][2][q] + bh2));
                    float hp = hprevf[idx];
                    float h  = (1.f - zg) * ng + zg * hp;
                    float res = residf[idx];
                    float v = (h + res) * 0.70710678f;
                    float y = v > 0.f ? v : 0.2f * v;
                    if (cvalid) {
                        houtf[idx] = h;
                        houtb[idx] = f2bf(h);
                        if (layer == 2) {
                            out[(size_t)t * BD + idx] = y;
                        } else {
                            hin_f[(size_t)(layer * 2 + (t & 1)) * BD + idx]  = y;
                            hin_bf[(size_t)(layer * 2 + (t & 1)) * BD + idx] = f2bf(y);
                        }
                    }
                }
            }
        }
        gbar(bar_cnt, bar_gen, NWG);
    }
}

extern "C" void kernel_launch(void* const* d_in, const int* in_sizes, int n_in,
                              void* d_out, int out_size, void* d_ws, size_t ws_size,
                              hipStream_t stream) {
    const float* x   = (const float*)d_in[0];
    const float* Wih = (const float*)d_in[1];
    const float* Whh = (const float*)d_in[2];
    const float* bih = (const float*)d_in[3];
    const float* bhh = (const float*)d_in[4];
    float* out = (float*)d_out;

    char* ws = (char*)d_ws;
    size_t off = 0;
    auto alloc = [&](size_t bytes) -> void* {
        void* p = ws + off;
        off += (bytes + 255) & ~(size_t)255;
        return p;
    };

    const int NX = TT * BD;  // 33,554,432
    unsigned short* xbf = (unsigned short*)alloc((size_t)NX * 2);

    size_t zstart = off;
    unsigned short* ring_bf = (unsigned short*)alloc((size_t)10 * BD * 2);
    float*          ring_f  = (float*)alloc((size_t)10 * BD * 4);
    unsigned short* hin_bf  = (unsigned short*)alloc((size_t)4 * BD * 2);
    float*          hin_f   = (float*)alloc((size_t)4 * BD * 4);
    unsigned*       bar     = (unsigned*)alloc(256);
    size_t zbytes = off - zstart;

    cvt_f32_bf16<<<NX / 8 / 256, 256, 0, stream>>>(x, xbf, NX);
    hipMemsetAsync(ws + zstart, 0, zbytes, stream);

    dgru_persistent<<<NWG, 256, 0, stream>>>(
        xbf, x, Wih, Whh, bih, bhh,
        ring_bf, ring_f, hin_bf, hin_f, out,
        bar, bar + 1);
}

// Round 3
// 14981.358 us; speedup vs baseline: 2.0708x; 1.1686x over previous
//
#include <hip/hip_runtime.h>
#include <hip/hip_bf16.h>

#define TT 256
#define D 1024
#define BD (128 * 1024)
#define NWPL 85
#define NWG 256
#define NUSED 255
#define STEPS (TT + 2)
#define ROWLEN 1032  // 1024 + 8 bf16 pad

typedef __attribute__((ext_vector_type(8))) short bf16x8;
typedef __attribute__((ext_vector_type(4))) float f32x4;

__device__ __forceinline__ unsigned short f2bf(float f) {
    __hip_bfloat16 h = __float2bfloat16(f);
    return *reinterpret_cast<unsigned short*>(&h);
}
__device__ __forceinline__ float bf2f(unsigned short u) {
    unsigned v = (unsigned)u << 16;
    return __builtin_bit_cast(float, v);
}

__global__ __launch_bounds__(256) void cvt_f32_bf16(const float* __restrict__ in,
                                                    unsigned short* __restrict__ out, int n) {
    int i = (blockIdx.x * 256 + threadIdx.x) * 8;
    if (i + 8 <= n) {
        float4 a = *(const float4*)(in + i);
        float4 b = *(const float4*)(in + i + 4);
        unsigned short t[8] = { f2bf(a.x), f2bf(a.y), f2bf(a.z), f2bf(a.w),
                                f2bf(b.x), f2bf(b.y), f2bf(b.z), f2bf(b.w) };
        *(uint4*)(out + i) = *(const uint4*)t;
    }
}

__device__ __forceinline__ void gbar(unsigned* cnt, unsigned* gen, unsigned nwg) {
    __syncthreads();
    if (threadIdx.x == 0) {
        __threadfence();
        unsigned g = __hip_atomic_load(gen, __ATOMIC_RELAXED, __HIP_MEMORY_SCOPE_AGENT);
        unsigned a = __hip_atomic_fetch_add(cnt, 1u, __ATOMIC_ACQ_REL, __HIP_MEMORY_SCOPE_AGENT);
        if (a == nwg - 1u) {
            __hip_atomic_store(cnt, 0u, __ATOMIC_RELAXED, __HIP_MEMORY_SCOPE_AGENT);
            __hip_atomic_store(gen, g + 1u, __ATOMIC_RELEASE, __HIP_MEMORY_SCOPE_AGENT);
        } else {
            while (__hip_atomic_load(gen, __ATOMIC_ACQUIRE, __HIP_MEMORY_SCOPE_AGENT) == g)
                __builtin_amdgcn_s_sleep(2);
        }
        __threadfence();
    }
    __syncthreads();
}

// Persistent skewed dilated-GRU, XCD-packed, deep-prefetch.
__global__ __launch_bounds__(256, 1) void dgru_persistent(
    const unsigned short* __restrict__ xbf,
    const float* __restrict__ Wih, const float* __restrict__ Whh,
    const float* __restrict__ bih, const float* __restrict__ bhh,
    unsigned short* __restrict__ ring_bf, float* __restrict__ ring_f,
    unsigned short* __restrict__ hin_bf, float* __restrict__ hin_f,
    float* __restrict__ out,
    unsigned* __restrict__ bar_cnt, unsigned* __restrict__ bar_gen)
{
    __shared__ unsigned short wlds[78 * ROWLEN];  // 160,992 B

    // XCD-packing: assume wg -> XCD is (blockIdx % 8). p enumerates slices so each
    // layer's 85 slices sit on ~3 contiguous XCDs.
    const int p = 32 * (blockIdx.x & 7) + (blockIdx.x >> 3);
    if (p >= NUSED) {  // one spare WG: barrier-only
        for (int s = 0; s < STEPS; ++s) gbar(bar_cnt, bar_gen, NWG);
        return;
    }
    const int layer = p / NWPL;
    const int u     = p % NWPL;
    const int ncols = (u < 4) ? 13 : 12;
    const int c0    = u * 12 + (u < 4 ? u : 4);

    // ---- one-time: weight slice fp32 -> bf16 -> LDS (stationary)
    {
        const float* w0 = Wih + (size_t)layer * 3 * D * D;
        const float* w1 = Whh + (size_t)layer * 3 * D * D;
        const int nrows = 6 * ncols;
        for (int rid = 0; rid < nrows; ++rid) {
            int m   = rid / (3 * ncols);
            int rem = rid - m * 3 * ncols;
            int g   = rem / ncols;
            int c   = rem - g * ncols;
            const float* src = (m ? w1 : w0) + ((size_t)g * D + c0 + c) * D + threadIdx.x * 4;
            float4 v = *(const float4*)src;
            ushort4 o = { f2bf(v.x), f2bf(v.y), f2bf(v.z), f2bf(v.w) };
            *(ushort4*)&wlds[rid * ROWLEN + threadIdx.x * 4] = o;
        }
        __syncthreads();
    }

    const int tid  = threadIdx.x;
    const int wave = tid >> 6;
    const int lane = tid & 63;
    const int r15  = lane & 15;
    const int kq   = lane >> 4;
    const int kq8  = kq * 8;
    const int c_cl = (r15 < ncols) ? r15 : (ncols - 1);
    const bool cvalid = r15 < ncols;
    const int col  = c0 + c_cl;

    const float bi0 = bih[layer * 3 * D + col];
    const float bi1 = bih[layer * 3 * D + D + col];
    const float bi2 = bih[layer * 3 * D + 2 * D + col];
    const float bh0 = bhh[layer * 3 * D + col];
    const float bh1 = bhh[layer * 3 * D + D + col];
    const float bh2 = bhh[layer * 3 * D + 2 * D + col];
    const float bs0 = bi0 + bh0;
    const float bs1 = bi1 + bh1;

    const unsigned short* bp[6];
    #pragma unroll
    for (int mg = 0; mg < 6; ++mg) bp[mg] = wlds + (mg * ncols + c_cl) * ROWLEN;

    const int arow_off0 = (wave * 32 + r15) * D;
    const int arow_off1 = (wave * 32 + 16 + r15) * D;

    const int R  = (layer == 0) ? 2 : (layer == 1 ? 3 : 5);
    const int rb = (layer == 0) ? 0 : (layer == 1 ? 2 : 5);

    for (int s = 0; s < STEPS; ++s) {
        const int t = s - layer;
        if (t >= 0 && t < TT) {
            const unsigned short* hinb = layer ? hin_bf + (size_t)((layer - 1) * 2 + (t & 1)) * BD
                                               : xbf + (size_t)t * BD;
            const float* residf = hin_f + (size_t)((layer - 1) * 2 + (t & 1)) * BD;  // layer>=1
            const unsigned short* residb = xbf + (size_t)t * BD;                     // layer==0
            const int rs = (t + 1) % R, wsl = t % R;
            const unsigned short* hprevb = ring_bf + (size_t)(rb + rs) * BD;
            const float*  hprevf = ring_f + (size_t)(rb + rs) * BD;
            float*        houtf  = ring_f + (size_t)(rb + wsl) * BD;
            unsigned short* houtb = ring_bf + (size_t)(rb + wsl) * BD;

            // ---- epilogue operand prefetch (hide ~900cy under the GEMM)
            float hpv[8], rsv[8];
            #pragma unroll
            for (int rtl = 0; rtl < 2; ++rtl)
                #pragma unroll
                for (int q = 0; q < 4; ++q) {
                    const int row = wave * 32 + rtl * 16 + kq * 4 + q;
                    const size_t idx = (size_t)row * D + col;
                    hpv[rtl * 4 + q] = hprevf[idx];
                    rsv[rtl * 4 + q] = layer ? residf[idx] : bf2f(residb[idx]);
                }

            f32x4 acc[2][2][3] = {};
            bf16x8 A0[16], A1[16];

#define ISSUE1(Av, KS, SL) { \
            Av[(SL) * 4 + 0] = *(const bf16x8*)(hinb   + arow_off0 + (KS) * 32 + kq8); \
            Av[(SL) * 4 + 1] = *(const bf16x8*)(hprevb + arow_off0 + (KS) * 32 + kq8); \
            Av[(SL) * 4 + 2] = *(const bf16x8*)(hinb   + arow_off1 + (KS) * 32 + kq8); \
            Av[(SL) * 4 + 3] = *(const bf16x8*)(hprevb + arow_off1 + (KS) * 32 + kq8); }
#define ISSUEG(Av, BASE) { ISSUE1(Av, (BASE) + 0, 0) ISSUE1(Av, (BASE) + 1, 1) \
                           ISSUE1(Av, (BASE) + 2, 2) ISSUE1(Av, (BASE) + 3, 3) }
#define COMPG(Av, BASE) { _Pragma("unroll") for (int kk = 0; kk < 4; ++kk) { \
            bf16x8 Bv[6]; \
            _Pragma("unroll") for (int mg = 0; mg < 6; ++mg) \
                Bv[mg] = *(const bf16x8*)(bp[mg] + ((BASE) + kk) * 32 + kq8); \
            _Pragma("unroll") for (int g = 0; g < 3; ++g) { \
                acc[0][0][g] = __builtin_amdgcn_mfma_f32_16x16x32_bf16(Av[kk * 4 + 0], Bv[g],     acc[0][0][g], 0, 0, 0); \
                acc[0][1][g] = __builtin_amdgcn_mfma_f32_16x16x32_bf16(Av[kk * 4 + 1], Bv[3 + g], acc[0][1][g], 0, 0, 0); \
                acc[1][0][g] = __builtin_amdgcn_mfma_f32_16x16x32_bf16(Av[kk * 4 + 2], Bv[g],     acc[1][0][g], 0, 0, 0); \
                acc[1][1][g] = __builtin_amdgcn_mfma_f32_16x16x32_bf16(Av[kk * 4 + 3], Bv[3 + g], acc[1][1][g], 0, 0, 0); } } }

            ISSUEG(A0, 0);
            #pragma unroll
            for (int g8 = 0; g8 < 8; ++g8) {
                if ((g8 & 1) == 0) {
                    if (g8 < 7) ISSUEG(A1, (g8 + 1) * 4);
                    COMPG(A0, g8 * 4);
                } else {
                    if (g8 < 7) ISSUEG(A0, (g8 + 1) * 4);
                    COMPG(A1, g8 * 4);
                }
            }

            // ---- gates + residual
            #pragma unroll
            for (int rtl = 0; rtl < 2; ++rtl) {
                #pragma unroll
                for (int q = 0; q < 4; ++q) {
                    const int row = wave * 32 + rtl * 16 + kq * 4 + q;
                    const size_t idx = (size_t)row * D + col;
                    float xr = acc[rtl][0][0][q] + acc[rtl][1][0][q] + bs0;
                    float xz = acc[rtl][0][1][q] + acc[rtl][1][1][q] + bs1;
                    float rg = 1.f / (1.f + __expf(-xr));
                    float zg = 1.f / (1.f + __expf(-xz));
                    float ng = tanhf(acc[rtl][0][2][q] + bi2 + rg * (acc[rtl][1][2][q] + bh2));
                    float hp = hpv[rtl * 4 + q];
                    float h  = (1.f - zg) * ng + zg * hp;
                    float v = (h + rsv[rtl * 4 + q]) * 0.70710678f;
                    float y = v > 0.f ? v : 0.2f * v;
                    if (cvalid) {
                        houtf[idx] = h;
                        houtb[idx] = f2bf(h);
                        if (layer == 2) {
                            out[(size_t)t * BD + idx] = y;
                        } else {
                            hin_f[(size_t)(layer * 2 + (t & 1)) * BD + idx]  = y;
                            hin_bf[(size_t)(layer * 2 + (t & 1)) * BD + idx] = f2bf(y);
                        }
                    }
                }
            }
        }
        gbar(bar_cnt, bar_gen, NWG);
    }
}

extern "C" void kernel_launch(void* const* d_in, const int* in_sizes, int n_in,
                              void* d_out, int out_size, void* d_ws, size_t ws_size,
                              hipStream_t stream) {
    const float* x   = (const float*)d_in[0];
    const float* Wih = (const float*)d_in[1];
    const float* Whh = (const float*)d_in[2];
    const float* bih = (const float*)d_in[3];
    const float* bhh = (const float*)d_in[4];
    float* out = (float*)d_out;

    char* ws = (char*)d_ws;
    size_t off = 0;
    auto alloc = [&](size_t bytes) -> void* {
        void* p = ws + off;
        off += (bytes + 255) & ~(size_t)255;
        return p;
    };

    const int NX = TT * BD;
    unsigned short* xbf = (unsigned short*)alloc((size_t)NX * 2);

    size_t zstart = off;
    unsigned short* ring_bf = (unsigned short*)alloc((size_t)10 * BD * 2);
    float*          ring_f  = (float*)alloc((size_t)10 * BD * 4);
    unsigned short* hin_bf  = (unsigned short*)alloc((size_t)4 * BD * 2);
    float*          hin_f   = (float*)alloc((size_t)4 * BD * 4);
    unsigned*       bar     = (unsigned*)alloc(256);
    size_t zbytes = off - zstart;

    cvt_f32_bf16<<<NX / 8 / 256, 256, 0, stream>>>(x, xbf, NX);
    hipMemsetAsync(ws + zstart, 0, zbytes, stream);

    dgru_persistent<<<NWG, 256, 0, stream>>>(
        xbf, Wih, Whh, bih, bhh,
        ring_bf, ring_f, hin_bf, hin_f, out,
        bar, bar + 1);
}

// Round 4
// 6834.968 us; speedup vs baseline: 4.5389x; 2.1919x over previous
//
#include <hip/hip_runtime.h>
#include <hip/hip_bf16.h>

#define TT 256
#define D 1024
#define BD (128 * 1024)
#define NWPL 85
#define NWG 256
#define NUSED 255
#define STEPS (TT + 2)
#define ROWLEN 1032  // 1024 + 8 bf16 pad

typedef __attribute__((ext_vector_type(8))) short bf16x8;
typedef __attribute__((ext_vector_type(4))) float f32x4;

__device__ __forceinline__ unsigned short f2bf(float f) {
    __hip_bfloat16 h = __float2bfloat16(f);
    return *reinterpret_cast<unsigned short*>(&h);
}
__device__ __forceinline__ float bf2f(unsigned short u) {
    unsigned v = (unsigned)u << 16;
    return __builtin_bit_cast(float, v);
}

__global__ __launch_bounds__(256) void cvt_f32_bf16(const float* __restrict__ in,
                                                    unsigned short* __restrict__ out, int n) {
    int i = (blockIdx.x * 256 + threadIdx.x) * 8;
    if (i + 8 <= n) {
        float4 a = *(const float4*)(in + i);
        float4 b = *(const float4*)(in + i + 4);
        unsigned short t[8] = { f2bf(a.x), f2bf(a.y), f2bf(a.z), f2bf(a.w),
                                f2bf(b.x), f2bf(b.y), f2bf(b.z), f2bf(b.w) };
        *(uint4*)(out + i) = *(const uint4*)t;
    }
}

// Hierarchical grid barrier: 8 arrival lines (32 WGs each) -> master -> gen.
// bar layout (unsigned idx): xcnt[g] at g*32 (128B apart), master at 256, gen at 288.
__device__ __forceinline__ void gbar(unsigned* __restrict__ bar, int grp) {
    __syncthreads();  // drains vmcnt(0): all waves' stores acked before arrival
    if (threadIdx.x == 0) {
        unsigned* xcnt = bar + grp * 32;
        unsigned* mcnt = bar + 256;
        unsigned* gen  = bar + 288;
        // release: flush this XCD's L2 (cheap: epilogue stores are sc1/MALL-direct)
        __builtin_amdgcn_fence(__ATOMIC_RELEASE, "agent");
        unsigned g = __hip_atomic_load(gen, __ATOMIC_RELAXED, __HIP_MEMORY_SCOPE_AGENT);
        unsigned a = __hip_atomic_fetch_add(xcnt, 1u, __ATOMIC_RELAXED, __HIP_MEMORY_SCOPE_AGENT);
        if (a == 31u) {
            __hip_atomic_store(xcnt, 0u, __ATOMIC_RELAXED, __HIP_MEMORY_SCOPE_AGENT);
            unsigned m = __hip_atomic_fetch_add(mcnt, 1u, __ATOMIC_ACQ_REL, __HIP_MEMORY_SCOPE_AGENT);
            if (m == 7u) {
                __hip_atomic_store(mcnt, 0u, __ATOMIC_RELAXED, __HIP_MEMORY_SCOPE_AGENT);
                __hip_atomic_store(gen, g + 1u, __ATOMIC_RELEASE, __HIP_MEMORY_SCOPE_AGENT);
            }
        }
        while (__hip_atomic_load(gen, __ATOMIC_RELAXED, __HIP_MEMORY_SCOPE_AGENT) == g)
            __builtin_amdgcn_s_sleep(1);
        __builtin_amdgcn_fence(__ATOMIC_ACQUIRE, "agent");  // inv L1/L2
    }
    __syncthreads();
}

// Persistent skewed dilated-GRU, XCD-packed, deep-prefetch, MALL-direct stores.
__global__ __launch_bounds__(256, 1) void dgru_persistent(
    const unsigned short* __restrict__ xbf,
    const float* __restrict__ Wih, const float* __restrict__ Whh,
    const float* __restrict__ bih, const float* __restrict__ bhh,
    unsigned short* __restrict__ ring_bf, float* __restrict__ ring_f,
    unsigned short* __restrict__ hin_bf,
    float* __restrict__ out,
    unsigned* __restrict__ bar)
{
    __shared__ unsigned short wlds[78 * ROWLEN];  // 160,992 B

    const int grp = blockIdx.x & 7;
    // XCD-packing heuristic (perf only): p packs each layer's slices onto ~3 XCDs.
    const int p = 32 * grp + (blockIdx.x >> 3);
    if (p >= NUSED) {  // spare WG: barrier-only
        for (int s = 0; s < STEPS; ++s) gbar(bar, grp);
        return;
    }
    const int layer = p / NWPL;
    const int u     = p % NWPL;
    const int ncols = (u < 4) ? 13 : 12;
    const int c0    = u * 12 + (u < 4 ? u : 4);

    // ---- one-time: weight slice fp32 -> bf16 -> LDS (stationary)
    {
        const float* w0 = Wih + (size_t)layer * 3 * D * D;
        const float* w1 = Whh + (size_t)layer * 3 * D * D;
        const int nrows = 6 * ncols;
        for (int rid = 0; rid < nrows; ++rid) {
            int m   = rid / (3 * ncols);
            int rem = rid - m * 3 * ncols;
            int g   = rem / ncols;
            int c   = rem - g * ncols;
            const float* src = (m ? w1 : w0) + ((size_t)g * D + c0 + c) * D + threadIdx.x * 4;
            float4 v = *(const float4*)src;
            ushort4 o = { f2bf(v.x), f2bf(v.y), f2bf(v.z), f2bf(v.w) };
            *(ushort4*)&wlds[rid * ROWLEN + threadIdx.x * 4] = o;
        }
        __syncthreads();
    }

    const int tid  = threadIdx.x;
    const int wave = tid >> 6;
    const int lane = tid & 63;
    const int r15  = lane & 15;
    const int kq   = lane >> 4;
    const int kq8  = kq * 8;
    const int c_cl = (r15 < ncols) ? r15 : (ncols - 1);
    const bool cvalid = r15 < ncols;
    const int col  = c0 + c_cl;

    const float bi0 = bih[layer * 3 * D + col];
    const float bi1 = bih[layer * 3 * D + D + col];
    const float bi2 = bih[layer * 3 * D + 2 * D + col];
    const float bh0 = bhh[layer * 3 * D + col];
    const float bh1 = bhh[layer * 3 * D + D + col];
    const float bh2 = bhh[layer * 3 * D + 2 * D + col];
    const float bs0 = bi0 + bh0;
    const float bs1 = bi1 + bh1;

    const unsigned short* bp[6];
    #pragma unroll
    for (int mg = 0; mg < 6; ++mg) bp[mg] = wlds + (mg * ncols + c_cl) * ROWLEN;

    const int arow_off0 = (wave * 32 + r15) * D;
    const int arow_off1 = (wave * 32 + 16 + r15) * D;

    const int R  = (layer == 0) ? 2 : (layer == 1 ? 3 : 5);
    const int rb = (layer == 0) ? 0 : (layer == 1 ? 2 : 5);

    for (int s = 0; s < STEPS; ++s) {
        const int t = s - layer;
        if (t >= 0 && t < TT) {
            const unsigned short* hinb = layer ? hin_bf + (size_t)((layer - 1) * 2 + (t & 1)) * BD
                                               : xbf + (size_t)t * BD;
            const int rs = (t + 1) % R, wsl = t % R;
            const unsigned short* hprevb = ring_bf + (size_t)(rb + rs) * BD;
            const float*  hprevf = ring_f + (size_t)(rb + rs) * BD;
            float*        houtf  = ring_f + (size_t)(rb + wsl) * BD;
            unsigned short* houtb = ring_bf + (size_t)(rb + wsl) * BD;

            // ---- epilogue operand prefetch (hide latency under the GEMM)
            float hpv[8], rsv[8];
            #pragma unroll
            for (int rtl = 0; rtl < 2; ++rtl)
                #pragma unroll
                for (int q = 0; q < 4; ++q) {
                    const int row = wave * 32 + rtl * 16 + kq * 4 + q;
                    const size_t idx = (size_t)row * D + col;
                    hpv[rtl * 4 + q] = hprevf[idx];
                    rsv[rtl * 4 + q] = bf2f(hinb[idx]);  // residual == layer input
                }

            f32x4 acc[2][2][3] = {};
            bf16x8 A0[16], A1[16];

#define ISSUE1(Av, KS, SL) { \
            Av[(SL) * 4 + 0] = *(const bf16x8*)(hinb   + arow_off0 + (KS) * 32 + kq8); \
            Av[(SL) * 4 + 1] = *(const bf16x8*)(hprevb + arow_off0 + (KS) * 32 + kq8); \
            Av[(SL) * 4 + 2] = *(const bf16x8*)(hinb   + arow_off1 + (KS) * 32 + kq8); \
            Av[(SL) * 4 + 3] = *(const bf16x8*)(hprevb + arow_off1 + (KS) * 32 + kq8); }
#define ISSUEG(Av, BASE) { ISSUE1(Av, (BASE) + 0, 0) ISSUE1(Av, (BASE) + 1, 1) \
                           ISSUE1(Av, (BASE) + 2, 2) ISSUE1(Av, (BASE) + 3, 3) }
#define COMPG(Av, BASE) { _Pragma("unroll") for (int kk = 0; kk < 4; ++kk) { \
            bf16x8 Bv[6]; \
            _Pragma("unroll") for (int mg = 0; mg < 6; ++mg) \
                Bv[mg] = *(const bf16x8*)(bp[mg] + ((BASE) + kk) * 32 + kq8); \
            _Pragma("unroll") for (int g = 0; g < 3; ++g) { \
                acc[0][0][g] = __builtin_amdgcn_mfma_f32_16x16x32_bf16(Av[kk * 4 + 0], Bv[g],     acc[0][0][g], 0, 0, 0); \
                acc[0][1][g] = __builtin_amdgcn_mfma_f32_16x16x32_bf16(Av[kk * 4 + 1], Bv[3 + g], acc[0][1][g], 0, 0, 0); \
                acc[1][0][g] = __builtin_amdgcn_mfma_f32_16x16x32_bf16(Av[kk * 4 + 2], Bv[g],     acc[1][0][g], 0, 0, 0); \
                acc[1][1][g] = __builtin_amdgcn_mfma_f32_16x16x32_bf16(Av[kk * 4 + 3], Bv[3 + g], acc[1][1][g], 0, 0, 0); } } }

            ISSUEG(A0, 0);
            #pragma unroll
            for (int g8 = 0; g8 < 8; ++g8) {
                if ((g8 & 1) == 0) {
                    if (g8 < 7) ISSUEG(A1, (g8 + 1) * 4);
                    COMPG(A0, g8 * 4);
                } else {
                    if (g8 < 7) ISSUEG(A0, (g8 + 1) * 4);
                    COMPG(A1, g8 * 4);
                }
            }

            // ---- gates + residual; stores are agent-scope (sc1 -> MALL, L2 stays clean)
            #pragma unroll
            for (int rtl = 0; rtl < 2; ++rtl) {
                #pragma unroll
                for (int q = 0; q < 4; ++q) {
                    const int row = wave * 32 + rtl * 16 + kq * 4 + q;
                    const size_t idx = (size_t)row * D + col;
                    float xr = acc[rtl][0][0][q] + acc[rtl][1][0][q] + bs0;
                    float xz = acc[rtl][0][1][q] + acc[rtl][1][1][q] + bs1;
                    float rg = 1.f / (1.f + __expf(-xr));
                    float zg = 1.f / (1.f + __expf(-xz));
                    float ng = tanhf(acc[rtl][0][2][q] + bi2 + rg * (acc[rtl][1][2][q] + bh2));
                    float hp = hpv[rtl * 4 + q];
                    float h  = (1.f - zg) * ng + zg * hp;
                    float v = (h + rsv[rtl * 4 + q]) * 0.70710678f;
                    float y = v > 0.f ? v : 0.2f * v;
                    if (cvalid) {
                        __hip_atomic_store(&houtf[idx], h, __ATOMIC_RELAXED, __HIP_MEMORY_SCOPE_AGENT);
                        __hip_atomic_store(&houtb[idx], f2bf(h), __ATOMIC_RELAXED, __HIP_MEMORY_SCOPE_AGENT);
                        if (layer == 2) {
                            __hip_atomic_store(&out[(size_t)t * BD + idx], y, __ATOMIC_RELAXED, __HIP_MEMORY_SCOPE_AGENT);
                        } else {
                            __hip_atomic_store(&hin_bf[(size_t)(layer * 2 + (t & 1)) * BD + idx],
                                               f2bf(y), __ATOMIC_RELAXED, __HIP_MEMORY_SCOPE_AGENT);
                        }
                    }
                }
            }
        }
        gbar(bar, grp);
    }
}

extern "C" void kernel_launch(void* const* d_in, const int* in_sizes, int n_in,
                              void* d_out, int out_size, void* d_ws, size_t ws_size,
                              hipStream_t stream) {
    const float* x   = (const float*)d_in[0];
    const float* Wih = (const float*)d_in[1];
    const float* Whh = (const float*)d_in[2];
    const float* bih = (const float*)d_in[3];
    const float* bhh = (const float*)d_in[4];
    float* out = (float*)d_out;

    char* ws = (char*)d_ws;
    size_t off = 0;
    auto alloc = [&](size_t bytes) -> void* {
        void* p = ws + off;
        off += (bytes + 255) & ~(size_t)255;
        return p;
    };

    const int NX = TT * BD;
    unsigned short* xbf = (unsigned short*)alloc((size_t)NX * 2);

    size_t zstart = off;
    unsigned short* ring_bf = (unsigned short*)alloc((size_t)10 * BD * 2);
    float*          ring_f  = (float*)alloc((size_t)10 * BD * 4);
    unsigned short* hin_bf  = (unsigned short*)alloc((size_t)4 * BD * 2);
    unsigned*       bar     = (unsigned*)alloc(2048);
    size_t zbytes = off - zstart;

    cvt_f32_bf16<<<NX / 8 / 256, 256, 0, stream>>>(x, xbf, NX);
    hipMemsetAsync(ws + zstart, 0, zbytes, stream);

    dgru_persistent<<<NWG, 256, 0, stream>>>(
        xbf, Wih, Whh, bih, bhh,
        ring_bf, ring_f, hin_bf, out,
        bar);
}

// Round 5
// 5818.739 us; speedup vs baseline: 5.3316x; 1.1746x over previous
//
#include <hip/hip_runtime.h>
#include <hip/hip_bf16.h>

#define TT 256
#define D 1024
#define BD (128 * 1024)
#define NWPL 85
#define NWG 256
#define NUSED 255
#define STEPS (TT + 2)
#define ROWLEN 1040  // 1024 + 16 pad: bank stride 8 mod 32 -> 4-way (was 8-way at 1032)

typedef __attribute__((ext_vector_type(8))) short bf16x8;
typedef __attribute__((ext_vector_type(4))) float f32x4;

__device__ __forceinline__ unsigned short f2bf(float f) {
    __hip_bfloat16 h = __float2bfloat16(f);
    return *reinterpret_cast<unsigned short*>(&h);
}
__device__ __forceinline__ float bf2f(unsigned short u) {
    unsigned v = (unsigned)u << 16;
    return __builtin_bit_cast(float, v);
}

__global__ __launch_bounds__(256) void cvt_f32_bf16(const float* __restrict__ in,
                                                    unsigned short* __restrict__ out, int n) {
    int i = (blockIdx.x * 256 + threadIdx.x) * 8;
    if (i + 8 <= n) {
        float4 a = *(const float4*)(in + i);
        float4 b = *(const float4*)(in + i + 4);
        unsigned short t[8] = { f2bf(a.x), f2bf(a.y), f2bf(a.z), f2bf(a.w),
                                f2bf(b.x), f2bf(b.y), f2bf(b.z), f2bf(b.w) };
        *(uint4*)(out + i) = *(const uint4*)t;
    }
}

// Hierarchical grid barrier: 8 arrival lines (32 WGs each) -> master -> gen.
__device__ __forceinline__ void gbar(unsigned* __restrict__ bar, int grp) {
    __syncthreads();  // drains vmcnt(0): all waves' stores acked before arrival
    if (threadIdx.x == 0) {
        unsigned* xcnt = bar + grp * 32;
        unsigned* mcnt = bar + 256;
        unsigned* gen  = bar + 288;
        __builtin_amdgcn_fence(__ATOMIC_RELEASE, "agent");
        unsigned g = __hip_atomic_load(gen, __ATOMIC_RELAXED, __HIP_MEMORY_SCOPE_AGENT);
        unsigned a = __hip_atomic_fetch_add(xcnt, 1u, __ATOMIC_RELAXED, __HIP_MEMORY_SCOPE_AGENT);
        if (a == 31u) {
            __hip_atomic_store(xcnt, 0u, __ATOMIC_RELAXED, __HIP_MEMORY_SCOPE_AGENT);
            unsigned m = __hip_atomic_fetch_add(mcnt, 1u, __ATOMIC_ACQ_REL, __HIP_MEMORY_SCOPE_AGENT);
            if (m == 7u) {
                __hip_atomic_store(mcnt, 0u, __ATOMIC_RELAXED, __HIP_MEMORY_SCOPE_AGENT);
                __hip_atomic_store(gen, g + 1u, __ATOMIC_RELEASE, __HIP_MEMORY_SCOPE_AGENT);
            }
        }
        while (__hip_atomic_load(gen, __ATOMIC_RELAXED, __HIP_MEMORY_SCOPE_AGENT) == g)
            __builtin_amdgcn_s_sleep(1);
        __builtin_amdgcn_fence(__ATOMIC_ACQUIRE, "agent");  // inv L1/L2
    }
    __syncthreads();
}

// Persistent skewed dilated-GRU, XCD-packed, pinned 3-deep prefetch, MALL-direct stores.
__global__ __launch_bounds__(256, 1) void dgru_persistent(
    const unsigned short* __restrict__ xbf,
    const float* __restrict__ Wih, const float* __restrict__ Whh,
    const float* __restrict__ bih, const float* __restrict__ bhh,
    unsigned short* __restrict__ ring_bf, float* __restrict__ ring_f,
    unsigned short* __restrict__ hin_bf,
    float* __restrict__ out,
    unsigned* __restrict__ bar)
{
    __shared__ unsigned short wlds[78 * ROWLEN];  // 162,240 B? no: 78*1040*2 = 162,240 > 160K!
    // NOTE: 78 rows only when ncols==13; allocate exactly: 6*13=78 rows max.
    // 78 * 1040 * 2 = 162,240 B exceeds 163,840? No: 162,240 < 163,840 (160 KiB). OK.

    const int grp = blockIdx.x & 7;
    const int p = 32 * grp + (blockIdx.x >> 3);  // XCD-packing heuristic (perf only)
    if (p >= NUSED) {
        for (int s = 0; s < STEPS; ++s) gbar(bar, grp);
        return;
    }
    const int layer = p / NWPL;
    const int u     = p % NWPL;
    const int ncols = (u < 4) ? 13 : 12;
    const int c0    = u * 12 + (u < 4 ? u : 4);

    // ---- one-time: weight slice fp32 -> bf16 -> LDS (stationary)
    {
        const float* w0 = Wih + (size_t)layer * 3 * D * D;
        const float* w1 = Whh + (size_t)layer * 3 * D * D;
        const int nrows = 6 * ncols;
        for (int rid = 0; rid < nrows; ++rid) {
            int m   = rid / (3 * ncols);
            int rem = rid - m * 3 * ncols;
            int g   = rem / ncols;
            int c   = rem - g * ncols;
            const float* src = (m ? w1 : w0) + ((size_t)g * D + c0 + c) * D + threadIdx.x * 4;
            float4 v = *(const float4*)src;
            ushort4 o = { f2bf(v.x), f2bf(v.y), f2bf(v.z), f2bf(v.w) };
            *(ushort4*)&wlds[rid * ROWLEN + threadIdx.x * 4] = o;
        }
        __syncthreads();
    }

    const int tid  = threadIdx.x;
    const int wave = tid >> 6;
    const int lane = tid & 63;
    const int r15  = lane & 15;
    const int kq   = lane >> 4;
    const int kq8  = kq * 8;
    const int c_cl = (r15 < ncols) ? r15 : (ncols - 1);
    const bool cvalid = r15 < ncols;
    const int col  = c0 + c_cl;

    const float bi2 = bih[layer * 3 * D + 2 * D + col];
    const float bh0 = bhh[layer * 3 * D + col];
    const float bh1 = bhh[layer * 3 * D + D + col];
    const float bh2 = bhh[layer * 3 * D + 2 * D + col];
    const float bs0 = bih[layer * 3 * D + col] + bh0;
    const float bs1 = bih[layer * 3 * D + D + col] + bh1;

    const unsigned short* bp[6];
    #pragma unroll
    for (int mg = 0; mg < 6; ++mg) bp[mg] = wlds + (mg * ncols + c_cl) * ROWLEN;

    const int arow_off0 = (wave * 32 + r15) * D;
    const int arow_off1 = (wave * 32 + 16 + r15) * D;

    const int R  = (layer == 0) ? 2 : (layer == 1 ? 3 : 5);
    const int rb = (layer == 0) ? 0 : (layer == 1 ? 2 : 5);

    for (int s = 0; s < STEPS; ++s) {
        const int t = s - layer;
        if (t >= 0 && t < TT) {
            const unsigned short* hinb = layer ? hin_bf + (size_t)((layer - 1) * 2 + (t & 1)) * BD
                                               : xbf + (size_t)t * BD;
            const int rs = (t + 1) % R, wsl = t % R;
            const unsigned short* hprevb = ring_bf + (size_t)(rb + rs) * BD;
            const float*  hprevf = ring_f + (size_t)(rb + rs) * BD;
            float*        houtf  = ring_f + (size_t)(rb + wsl) * BD;
            unsigned short* houtb = ring_bf + (size_t)(rb + wsl) * BD;

            // ---- epilogue operand prefetch (returns under the GEMM)
            float hpv[8], rsv[8];
            #pragma unroll
            for (int rtl = 0; rtl < 2; ++rtl)
                #pragma unroll
                for (int q = 0; q < 4; ++q) {
                    const int row = wave * 32 + rtl * 16 + kq * 4 + q;
                    const size_t idx = (size_t)row * D + col;
                    hpv[rtl * 4 + q] = hprevf[idx];
                    rsv[rtl * 4 + q] = bf2f(hinb[idx]);
                }

            f32x4 acc[2][2][3] = {};
            bf16x8 A0[16], A1[16], A2[16];

#define ISSUE1(Av, KS, SL) { \
            Av[(SL) * 4 + 0] = *(const bf16x8*)(hinb   + arow_off0 + (KS) * 32 + kq8); \
            Av[(SL) * 4 + 1] = *(const bf16x8*)(hprevb + arow_off0 + (KS) * 32 + kq8); \
            Av[(SL) * 4 + 2] = *(const bf16x8*)(hinb   + arow_off1 + (KS) * 32 + kq8); \
            Av[(SL) * 4 + 3] = *(const bf16x8*)(hprevb + arow_off1 + (KS) * 32 + kq8); }
#define ISSUEG(Av, BASE) { ISSUE1(Av, (BASE) + 0, 0) ISSUE1(Av, (BASE) + 1, 1) \
                           ISSUE1(Av, (BASE) + 2, 2) ISSUE1(Av, (BASE) + 3, 3) \
                           __builtin_amdgcn_sched_barrier(0); }
#define COMPG(Av, BASE) { _Pragma("unroll") for (int kk = 0; kk < 4; ++kk) { \
            bf16x8 Bv[6]; \
            _Pragma("unroll") for (int mg = 0; mg < 6; ++mg) \
                Bv[mg] = *(const bf16x8*)(bp[mg] + ((BASE) + kk) * 32 + kq8); \
            _Pragma("unroll") for (int g = 0; g < 3; ++g) { \
                acc[0][0][g] = __builtin_amdgcn_mfma_f32_16x16x32_bf16(Av[kk * 4 + 0], Bv[g],     acc[0][0][g], 0, 0, 0); \
                acc[0][1][g] = __builtin_amdgcn_mfma_f32_16x16x32_bf16(Av[kk * 4 + 1], Bv[3 + g], acc[0][1][g], 0, 0, 0); \
                acc[1][0][g] = __builtin_amdgcn_mfma_f32_16x16x32_bf16(Av[kk * 4 + 2], Bv[g],     acc[1][0][g], 0, 0, 0); \
                acc[1][1][g] = __builtin_amdgcn_mfma_f32_16x16x32_bf16(Av[kk * 4 + 3], Bv[3 + g], acc[1][1][g], 0, 0, 0); } } \
            __builtin_amdgcn_sched_barrier(0); }

            // 3-deep pinned pipeline: issue g, g+1, g+2 up-front; steady state
            // re-issues into the set just consumed (~2 compute-groups of cover).
            ISSUEG(A0, 0);  ISSUEG(A1, 4);  ISSUEG(A2, 8);
            COMPG(A0, 0);   ISSUEG(A0, 12);
            COMPG(A1, 4);   ISSUEG(A1, 16);
            COMPG(A2, 8);   ISSUEG(A2, 20);
            COMPG(A0, 12);  ISSUEG(A0, 24);
            COMPG(A1, 16);  ISSUEG(A1, 28);
            COMPG(A2, 20);
            COMPG(A0, 24);
            COMPG(A1, 28);

            // ---- gates + residual; sc1 stores (MALL-direct, L2 stays clean)
            #pragma unroll
            for (int rtl = 0; rtl < 2; ++rtl) {
                #pragma unroll
                for (int q = 0; q < 4; ++q) {
                    const int row = wave * 32 + rtl * 16 + kq * 4 + q;
                    const size_t idx = (size_t)row * D + col;
                    float xr = acc[rtl][0][0][q] + acc[rtl][1][0][q] + bs0;
                    float xz = acc[rtl][0][1][q] + acc[rtl][1][1][q] + bs1;
                    float rg = 1.f / (1.f + __expf(-xr));
                    float zg = 1.f / (1.f + __expf(-xz));
                    float ng = tanhf(acc[rtl][0][2][q] + bi2 + rg * (acc[rtl][1][2][q] + bh2));
                    float hp = hpv[rtl * 4 + q];
                    float h  = (1.f - zg) * ng + zg * hp;
                    float v = (h + rsv[rtl * 4 + q]) * 0.70710678f;
                    float y = v > 0.f ? v : 0.2f * v;
                    if (cvalid) {
                        __hip_atomic_store(&houtf[idx], h, __ATOMIC_RELAXED, __HIP_MEMORY_SCOPE_AGENT);
                        __hip_atomic_store(&houtb[idx], f2bf(h), __ATOMIC_RELAXED, __HIP_MEMORY_SCOPE_AGENT);
                        if (layer == 2) {
                            __hip_atomic_store(&out[(size_t)t * BD + idx], y, __ATOMIC_RELAXED, __HIP_MEMORY_SCOPE_AGENT);
                        } else {
                            __hip_atomic_store(&hin_bf[(size_t)(layer * 2 + (t & 1)) * BD + idx],
                                               f2bf(y), __ATOMIC_RELAXED, __HIP_MEMORY_SCOPE_AGENT);
                        }
                    }
                }
            }
        }
        gbar(bar, grp);
    }
}

extern "C" void kernel_launch(void* const* d_in, const int* in_sizes, int n_in,
                              void* d_out, int out_size, void* d_ws, size_t ws_size,
                              hipStream_t stream) {
    const float* x   = (const float*)d_in[0];
    const float* Wih = (const float*)d_in[1];
    const float* Whh = (const float*)d_in[2];
    const float* bih = (const float*)d_in[3];
    const float* bhh = (const float*)d_in[4];
    float* out = (float*)d_out;

    char* ws = (char*)d_ws;
    size_t off = 0;
    auto alloc = [&](size_t bytes) -> void* {
        void* p = ws + off;
        off += (bytes + 255) & ~(size_t)255;
        return p;
    };

    const int NX = TT * BD;
    unsigned short* xbf = (unsigned short*)alloc((size_t)NX * 2);

    size_t zstart = off;
    unsigned short* ring_bf = (unsigned short*)alloc((size_t)10 * BD * 2);
    float*          ring_f  = (float*)alloc((size_t)10 * BD * 4);
    unsigned short* hin_bf  = (unsigned short*)alloc((size_t)4 * BD * 2);
    unsigned*       bar     = (unsigned*)alloc(2048);
    size_t zbytes = off - zstart;

    cvt_f32_bf16<<<NX / 8 / 256, 256, 0, stream>>>(x, xbf, NX);
    hipMemsetAsync(ws + zstart, 0, zbytes, stream);

    dgru_persistent<<<NWG, 256, 0, stream>>>(
        xbf, Wih, Whh, bih, bhh,
        ring_bf, ring_f, hin_bf, out,
        bar);
}